// Round 1
// baseline (1024.153 us; speedup 1.0000x reference)
//
#include <hip/hip_runtime.h>

// Problem dims
#define NB 32
#define TT 256
#define VV 25
#define TV 6400          // T*V
#define NSTR 1638400     // 256 * 6400 (per-n stride in x / out)

// ws float offsets (16B-aligned segments)
#define OFF_W1 0         // [3][64][64] (s,c,o), g3-folded
#define OFF_W3 12288     // [3][64][64] (s,c,o), g5-folded
#define OFF_WF 24576     // [64][64]    (c,o),   g4-folded
#define OFF_A1 28672     // [3][25][25]
#define OFF_A3 30720     // [3][25][25] (padded seg)
#define OFF_WO 32768     // [256][256]  (k,o),   g2-folded
#define OFF_SH1 98304    // [64]
#define OFF_SH3 98368    // [64]
#define OFF_SH2 98432    // [64]

__global__ __launch_bounds__(256) void prep_kernel(
    const float* __restrict__ A, const float* __restrict__ PA1, const float* __restrict__ PA3,
    const float* __restrict__ wd, const float* __restrict__ bd, const float* __restrict__ wg,
    const float* __restrict__ g3, const float* __restrict__ b3,
    const float* __restrict__ wf, const float* __restrict__ g4, const float* __restrict__ b4,
    const float* __restrict__ wh, const float* __restrict__ bh, const float* __restrict__ wk,
    const float* __restrict__ g5, const float* __restrict__ b5,
    const float* __restrict__ w_out, const float* __restrict__ g2,
    float* __restrict__ ws)
{
    int idx = blockIdx.x * 256 + threadIdx.x;
    if (idx < 12288) {                       // W1[s][c][o] = g3[o] * sum_p wg[o, s*64+p] * wd[s,p,c]
        int s = idx >> 12, c = (idx >> 6) & 63, o = idx & 63;
        float acc = 0.f;
        for (int p = 0; p < 64; ++p) acc += wg[o * 192 + s * 64 + p] * wd[(s * 64 + p) * 64 + c];
        ws[OFF_W1 + idx] = g3[o] * acc;
    } else if (idx < 24576) {                // W3 from wk, wh, g5
        int j = idx - 12288;
        int s = j >> 12, c = (j >> 6) & 63, o = j & 63;
        float acc = 0.f;
        for (int p = 0; p < 64; ++p) acc += wk[o * 192 + s * 64 + p] * wh[(s * 64 + p) * 64 + c];
        ws[OFF_W3 + j] = g5[o] * acc;
    } else if (idx < 28672) {                // Wf[c][o] = g4[o]*wf[o][c]
        int j = idx - 24576;
        int c = j >> 6, o = j & 63;
        ws[OFF_WF + j] = g4[o] * wf[o * 64 + c];
    } else if (idx < 30547) {                // A1 = A + PA1
        int j = idx - 28672;
        ws[OFF_A1 + j] = A[j] + PA1[j];
    } else if (idx < 32422) {                // A3 = A + PA3
        int j = idx - 30547;
        ws[OFF_A3 + j] = A[j] + PA3[j];
    } else if (idx < 97958) {                // WO[k][o] = g2[o]*w_out[o][k]
        int j = idx - 32422;
        int k = j >> 8, o = j & 255;
        ws[OFF_WO + j] = g2[o] * w_out[o * 256 + k];
    } else if (idx < 98022) {                // shift1[o] = g3*(wg·bd) + b3
        int o = idx - 97958;
        float acc = 0.f;
        for (int p = 0; p < 192; ++p) acc += wg[o * 192 + p] * bd[p];
        ws[OFF_SH1 + o] = g3[o] * acc + b3[o];
    } else if (idx < 98086) {                // shift3[o] = g5*(wk·bh) + b5
        int o = idx - 98022;
        float acc = 0.f;
        for (int p = 0; p < 192; ++p) acc += wk[o * 192 + p] * bh[p];
        ws[OFF_SH3 + o] = g5[o] * acc + b5[o];
    } else if (idx < 98150) {                // shift2 = b4
        int o = idx - 98086;
        ws[OFF_SH2 + o] = b4[o];
    }
}

// Fused subset graph-conv stage:
//   out[n, out_ch+o, t, w] = relu( sum_s sum_v A[s][v][w] * (sum_c W[s][c][o] * in[c][t][v]) + shift[o] )
// where in[c][t][v] = x[n, in_ch+c, t, v] (+ y_in[n, add_ch+c, t, v] if HAS2).
// Block: one (n, 4-t) tile, 256 threads = 64 o-lanes x 4 t. Per-thread U[s][v] in registers.
template<int S, bool HAS2>
__global__ __launch_bounds__(256, 3) void subset_kernel(
    const float* __restrict__ x, const float* __restrict__ y_in, float* __restrict__ out,
    const float* __restrict__ W, const float* __restrict__ Amat, const float* __restrict__ shift,
    int in_ch, int add_ch, int out_ch)
{
    const int n = blockIdx.y;
    const int t0 = blockIdx.x * 4;
    const int tid = threadIdx.x;

    __shared__ __align__(16) float Xs[4 * 64 * 28];   // [tl][c][28] padded rows
    __shared__ __align__(16) float As[S * 25 * 28];   // [(s*25+v)][28] padded rows

    // stage A into LDS
    for (int i = tid; i < S * 625; i += 256)
        As[(i / 25) * 28 + (i % 25)] = Amat[i];

    // stage X tile (coalesced dword loads; 100 contiguous floats per channel row)
    const size_t nb = (size_t)n * NSTR;
    const float* xb = x + nb + (size_t)in_ch * TV + t0 * 25;
    const float* ab = y_in + nb + (size_t)add_ch * TV + t0 * 25;
    for (int i = tid; i < 6400; i += 256) {
        int c = i / 100, q = i - c * 100;
        int tl = q / 25, v = q - tl * 25;
        float val = xb[c * TV + q];
        if (HAS2) val += ab[c * TV + q];
        Xs[(tl * 64 + c) * 28 + v] = val;
    }
    __syncthreads();

    const int o = tid & 63, tl = tid >> 6;

    // phase 1: U[s][v] = sum_c W[s][c][o] * X[c][tl][v]
    float U[S][25];
#pragma unroll
    for (int s = 0; s < S; ++s)
#pragma unroll
        for (int v = 0; v < 25; ++v) U[s][v] = 0.f;

    const float* Wp = W + o;
    const float* xbase = &Xs[tl * 1792];   // 64*28
#pragma unroll 2
    for (int c = 0; c < 64; ++c) {
        float xv[25];
#pragma unroll
        for (int q = 0; q < 6; ++q) {
            const float4 t4 = *(const float4*)&xbase[c * 28 + q * 4];
            xv[q * 4 + 0] = t4.x; xv[q * 4 + 1] = t4.y; xv[q * 4 + 2] = t4.z; xv[q * 4 + 3] = t4.w;
        }
        xv[24] = xbase[c * 28 + 24];
        float wsv[S];
#pragma unroll
        for (int s = 0; s < S; ++s) wsv[s] = Wp[(s * 64 + c) * 64];
#pragma unroll
        for (int s = 0; s < S; ++s)
#pragma unroll
            for (int v = 0; v < 25; ++v) U[s][v] += wsv[s] * xv[v];
    }

    // phase 2: acc[w] = sum_{s,v} U[s][v] * A[s][v][w]
    float acc[25];
#pragma unroll
    for (int w = 0; w < 25; ++w) acc[w] = 0.f;
#pragma unroll
    for (int s = 0; s < S; ++s) {
#pragma unroll
        for (int v = 0; v < 25; ++v) {
            const float u = U[s][v];
            const float* ar = &As[(s * 25 + v) * 28];
#pragma unroll
            for (int q = 0; q < 6; ++q) {
                const float4 a = *(const float4*)&ar[q * 4];
                acc[q * 4 + 0] += u * a.x; acc[q * 4 + 1] += u * a.y;
                acc[q * 4 + 2] += u * a.z; acc[q * 4 + 3] += u * a.w;
            }
            acc[24] += u * ar[24];
        }
    }

    const float sh = shift[o];
    __syncthreads();                       // all phase-1 LDS reads done; reuse Xs as Ys
    float* Ys = Xs;                        // [o][tl*25+w], 100 floats per o row
#pragma unroll
    for (int w = 0; w < 25; ++w)
        Ys[o * 100 + tl * 25 + w] = fmaxf(acc[w] + sh, 0.f);
    __syncthreads();

    // cooperative coalesced store (rows of 100 contiguous floats per out channel)
    float* ob = out + nb + (size_t)out_ch * TV + t0 * 25;
    for (int i = tid; i < 1600; i += 256) {
        int c = i / 25, r = i - c * 25;
        *(float4*)&ob[c * TV + r * 4] = *(const float4*)&Ys[c * 100 + r * 4];
    }
}

// Final: out[n,o,m] = relu( sum_k WO[k][o]*cat[n,k,m] + b2[o] + x[n,o,m] )
// cat channels 0..63 come from x, 64..255 from d_out (y1/y2/y3 in place).
// Block = (n, 128-m tile), 512 threads, all 256 o. Reads-all-then-writes => in-place safe.
__global__ __launch_bounds__(512, 4) void final_kernel(
    const float* __restrict__ x, float* __restrict__ dout,
    const float* __restrict__ WO, const float* __restrict__ b2)
{
    const int n = blockIdx.y;
    const int m0 = blockIdx.x * 128;
    const int tid = threadIdx.x;

    __shared__ __align__(16) float Xs[16 * 128];
    __shared__ __align__(16) float Ws[16 * 256];

    const int mlane = tid & 15, og = tid >> 4;     // og 0..31
    const int m8 = mlane * 8, o0 = og * 8;

    float acc[8][8];
#pragma unroll
    for (int i = 0; i < 8; ++i)
#pragma unroll
        for (int j = 0; j < 8; ++j) acc[i][j] = 0.f;

    const size_t nb = (size_t)n * NSTR;

    for (int kc = 0; kc < 16; ++kc) {
        // stage X: 16 channels x 128 m
        {
            const int kk = tid >> 5, f = tid & 31;
            const int k = kc * 16 + kk;
            const float* base = (k < 64) ? x : dout;
            *(float4*)&Xs[kk * 128 + f * 4] =
                *(const float4*)(base + nb + (size_t)k * TV + m0 + f * 4);
        }
        // stage W: 16 x 256
#pragma unroll
        for (int i = 0; i < 2; ++i) {
            const int idx = tid + i * 512;
            const int kk = idx >> 6, f = idx & 63;
            *(float4*)&Ws[kk * 256 + f * 4] =
                *(const float4*)(WO + (size_t)(kc * 16 + kk) * 256 + f * 4);
        }
        __syncthreads();

#pragma unroll 8
        for (int kk = 0; kk < 16; ++kk) {
            const float4 xa = *(const float4*)&Xs[kk * 128 + m8];
            const float4 xb2 = *(const float4*)&Xs[kk * 128 + m8 + 4];
            const float4 wa = *(const float4*)&Ws[kk * 256 + o0];
            const float4 wb = *(const float4*)&Ws[kk * 256 + o0 + 4];
            const float xm[8] = {xa.x, xa.y, xa.z, xa.w, xb2.x, xb2.y, xb2.z, xb2.w};
            const float wv[8] = {wa.x, wa.y, wa.z, wa.w, wb.x, wb.y, wb.z, wb.w};
#pragma unroll
            for (int oj = 0; oj < 8; ++oj)
#pragma unroll
                for (int mj = 0; mj < 8; ++mj)
                    acc[oj][mj] += wv[oj] * xm[mj];
        }
        __syncthreads();
    }

    // epilogue: bias + residual + relu, write all 256 channels of this m-tile
#pragma unroll
    for (int oj = 0; oj < 8; ++oj) {
        const int o = o0 + oj;
        const float sh = b2[o];
        const float* xr = x + nb + (size_t)o * TV + m0 + m8;
        float* ob = dout + nb + (size_t)o * TV + m0 + m8;
        const float4 r0 = *(const float4*)xr;
        const float4 r1 = *(const float4*)(xr + 4);
        float4 y0, y1v;
        y0.x = fmaxf(acc[oj][0] + sh + r0.x, 0.f);
        y0.y = fmaxf(acc[oj][1] + sh + r0.y, 0.f);
        y0.z = fmaxf(acc[oj][2] + sh + r0.z, 0.f);
        y0.w = fmaxf(acc[oj][3] + sh + r0.w, 0.f);
        y1v.x = fmaxf(acc[oj][4] + sh + r1.x, 0.f);
        y1v.y = fmaxf(acc[oj][5] + sh + r1.y, 0.f);
        y1v.z = fmaxf(acc[oj][6] + sh + r1.z, 0.f);
        y1v.w = fmaxf(acc[oj][7] + sh + r1.w, 0.f);
        *(float4*)ob = y0;
        *(float4*)(ob + 4) = y1v;
    }
}

extern "C" void kernel_launch(void* const* d_in, const int* in_sizes, int n_in,
                              void* d_out, int out_size, void* d_ws, size_t ws_size,
                              hipStream_t stream) {
    const float* x    = (const float*)d_in[0];
    const float* A    = (const float*)d_in[1];
    const float* PA1  = (const float*)d_in[2];
    const float* PA2  = (const float*)d_in[3];
    const float* PA3  = (const float*)d_in[4];
    const float* wd   = (const float*)d_in[5];
    const float* bd   = (const float*)d_in[6];
    const float* wg   = (const float*)d_in[7];
    const float* g3   = (const float*)d_in[8];
    const float* b3   = (const float*)d_in[9];
    const float* wf   = (const float*)d_in[10];
    const float* g4   = (const float*)d_in[11];
    const float* b4   = (const float*)d_in[12];
    const float* wh   = (const float*)d_in[13];
    const float* bh   = (const float*)d_in[14];
    const float* wk   = (const float*)d_in[15];
    const float* g5   = (const float*)d_in[16];
    const float* b5   = (const float*)d_in[17];
    const float* w_o  = (const float*)d_in[18];
    const float* g2   = (const float*)d_in[19];
    const float* b2   = (const float*)d_in[20];
    float* out = (float*)d_out;
    float* ws  = (float*)d_ws;

    prep_kernel<<<384, 256, 0, stream>>>(A, PA1, PA3, wd, bd, wg, g3, b3, wf, g4, b4,
                                         wh, bh, wk, g5, b5, w_o, g2, ws);

    dim3 sg(TT / 4, NB);
    // stage 1: xs[1] (ch 64) -> y1 at d_out ch 64
    subset_kernel<3, false><<<sg, 256, 0, stream>>>(x, x, out,
        ws + OFF_W1, ws + OFF_A1, ws + OFF_SH1, 64, 0, 64);
    // stage 2: xs[2] (ch 128) + y1 -> y2 at d_out ch 128
    subset_kernel<1, true><<<sg, 256, 0, stream>>>(x, out, out,
        ws + OFF_WF, PA2, ws + OFF_SH2, 128, 64, 128);
    // stage 3: xs[3] (ch 192) + y2 -> y3 at d_out ch 192
    subset_kernel<3, true><<<sg, 256, 0, stream>>>(x, out, out,
        ws + OFF_W3, ws + OFF_A3, ws + OFF_SH3, 192, 128, 192);
    // final 256x256 conv + BN + residual + relu (in-place cat in d_out)
    final_kernel<<<dim3(50, NB), 512, 0, stream>>>(x, out, ws + OFF_WO, b2);
}